// Round 12
// baseline (478.335 us; speedup 1.0000x reference)
//
#include <hip/hip_runtime.h>
#include <stdint.h>

#define M_TOK 256
#define N_OUT 16384
#define K_IN  4096
#define BM 128
#define BN 64
#define BK 64
#define NSTEPS (K_IN / BK)   // 64

#define AS1 __attribute__((address_space(1)))
#define AS3 __attribute__((address_space(3)))

typedef short v8s __attribute__((ext_vector_type(8)));
typedef float v16f __attribute__((ext_vector_type(16)));
typedef int   v4i __attribute__((ext_vector_type(4)));
typedef unsigned int uint;

__device__ __forceinline__ unsigned short rne_bf16(float f) {
  uint u = __float_as_uint(f);
  uint r = u + 0x7FFFu + ((u >> 16) & 1u);
  return (unsigned short)(r >> 16);
}
__device__ __forceinline__ float bfbits_to_f(uint h) {
  return __uint_as_float(h << 16);
}
// ints |v| <= 256 are exact in bf16: truncation of the f32 bits suffices
__device__ __forceinline__ uint pack_bf16(float a, float b) {
  return (__float_as_uint(a) >> 16) | (__float_as_uint(b) & 0xffff0000u);
}

// ---------------- kernel 1: exact dual-bf16 split of x (unchanged) ----------------
__global__ __launch_bounds__(256) void cast_kernel(
    const float* __restrict__ x, unsigned short* __restrict__ xhi,
    unsigned short* __restrict__ xlo) {
  const int i = (blockIdx.x * 256 + threadIdx.x) * 4;
  const float4 f = *(const float4*)(x + i);
  float fs[4] = {f.x, f.y, f.z, f.w};
  unsigned short h[4], l[4];
#pragma unroll
  for (int j = 0; j < 4; ++j) {
    h[j] = rne_bf16(fs[j]);
    l[j] = rne_bf16(fs[j] - bfbits_to_f(h[j]));
  }
  *(ushort4*)(xhi + i) = make_ushort4(h[0], h[1], h[2], h[3]);
  *(ushort4*)(xlo + i) = make_ushort4(l[0], l[1], l[2], l[3]);
}

// ---------------- kernel 1b: W pre-compaction int32/int8 -> bf16 ----------------
// Streaming pass: 256 MiB (or 64 MiB) -> 128 MiB bf16 in workspace. Removes the
// per-step load->convert->ds_write chain (and the 2x-redundant conversion) from
// the GEMM hot loop. 16 values/thread, fully coalesced (32 B out per thread).
__global__ __launch_bounds__(256) void wcompact_kernel(
    const void* __restrict__ wraw, unsigned short* __restrict__ wbf) {
  const int* wi = (const int*)wraw;
  const signed char* wb = (const signed char*)wraw;
  bool is32 = true;
#pragma unroll
  for (int i = 0; i < 16; ++i) {
    const int v = wi[i];
    is32 = is32 && (v >= -128) && (v <= 127);
  }
  const size_t vi = ((size_t)blockIdx.x * 256 + threadIdx.x) * 16;
  uint d[8];
  if (is32) {
    v4i a0 = *(const v4i*)(wi + vi);
    v4i a1 = *(const v4i*)(wi + vi + 4);
    v4i a2 = *(const v4i*)(wi + vi + 8);
    v4i a3 = *(const v4i*)(wi + vi + 12);
    d[0] = pack_bf16((float)a0.x, (float)a0.y);
    d[1] = pack_bf16((float)a0.z, (float)a0.w);
    d[2] = pack_bf16((float)a1.x, (float)a1.y);
    d[3] = pack_bf16((float)a1.z, (float)a1.w);
    d[4] = pack_bf16((float)a2.x, (float)a2.y);
    d[5] = pack_bf16((float)a2.z, (float)a2.w);
    d[6] = pack_bf16((float)a3.x, (float)a3.y);
    d[7] = pack_bf16((float)a3.z, (float)a3.w);
  } else {
    v4i a = *(const v4i*)(wb + vi);
    const signed char* bs = (const signed char*)&a;
#pragma unroll
    for (int p = 0; p < 8; ++p)
      d[p] = pack_bf16((float)bs[2 * p], (float)bs[2 * p + 1]);
  }
  v4i o0, o1;
  o0.x = (int)d[0]; o0.y = (int)d[1]; o0.z = (int)d[2]; o0.w = (int)d[3];
  o1.x = (int)d[4]; o1.y = (int)d[5]; o1.z = (int)d[6]; o1.w = (int)d[7];
  *(v4i*)(wbf + vi) = o0;
  *(v4i*)(wbf + vi + 8) = o1;
}

// ---------------- kernel 2: all-DMA dual-bf16 MFMA GEMM ----------------
// r4 champion geometry (BM=128 BN=64 BK=64, 512 blocks x 512 thr, 2 blocks/CU,
// 16 waves/CU) with the W hot-loop path DELETED: W is pre-compacted bf16, so
// both x and W stage via global_load_lds DMA (5 wave-instrs/wave/step), no W
// registers, no conv VALU, no dtype probe. dbuf + ONE barrier per step (r6
// skeleton): stage(t+1) into buf^1 -> compute(t) -> barrier; DMA hides under
// the full MFMA phase.
// LDS 80 KiB: x dbuf 2x32K @0 (128 rows x 256B: hi chunks 0-7 | lo 8-15);
// W dbuf 2x8K @65536 (32 rows x 256B; LDS row q packs n-rows 2q|2q+1).
// Chunk c of row r at pos c^(r&15): measured-zero bank conflicts (r0/r4/r11).
__global__ __launch_bounds__(512, 4) void gemm_kernel(
    const unsigned short* __restrict__ xhi, const unsigned short* __restrict__ xlo,
    const unsigned short* __restrict__ wbf, const float* __restrict__ scales,
    float* __restrict__ out) {
  __shared__ alignas(16) unsigned char smem[81920];
  const int tid = threadIdx.x;
  const int lane = tid & 63;
  const int wid = tid >> 6;

  // XCD swizzle: the 2 mb-blocks sharing one W strip are adjacent on one XCD.
  const int bid = blockIdx.x;
  const int logical = (bid & 7) * 64 + (bid >> 3);  // bijective for 512
  const int mb = logical & 1;
  const int nb = logical >> 1;
  const int m0 = mb * BM;
  const int n0 = nb * BN;

  // --- x staging: 4 gload_lds per thread (32 KiB/step); dest linear (base+lane*16),
  // swizzle realized by pre-swizzling the per-lane GLOBAL source chunk.
  const unsigned short* xsrc[4];
  uint xdst[4];
#pragma unroll
  for (int j = 0; j < 4; ++j) {
    const int s = wid * 4 + j;              // 0..31, each stages 4 rows (1 KiB)
    const int r = s * 4 + (lane >> 4);      // row 0..127
    const int c = (lane & 15) ^ (r & 15);   // chunk living at LDS pos lane&15
    xsrc[j] = (c >= 8 ? xlo : xhi) + (size_t)(m0 + r) * K_IN + (size_t)((c & 7) * 8);
    xdst[j] = (uint)(s * 1024);
  }

  // --- W staging: 1 gload_lds per wave (8 KiB/step total). Wave wid stages LDS
  // q-rows wid*4..+4; lane -> (q = wid*4 + lane>>4, pos p = lane&15), fetching
  // global chunk c = p ^ (q&15) of packed row q (= W rows 2q|2q+1).
  const int q_ = wid * 4 + (lane >> 4);
  const int cw = (lane & 15) ^ (q_ & 15);
  const unsigned short* wsrc =
      wbf + (size_t)(n0 + 2 * q_ + (cw >> 3)) * K_IN + (size_t)((cw & 7) * 8);
  const uint wdst = (uint)(wid * 1024);  // + lane*16 implicit (linear dest)

  // --- compute descriptors (mfma_f32_32x32x16_bf16; verified layouts)
  const int l31 = lane & 31, hi5 = lane >> 5;
  const int wm = (wid & 3) * 32;        // 4 m-waves
  const int wn = (wid >> 2) * 32;       // 2 n-waves
  const uint arow = (uint)((wm + l31) * 256);
  const uint ax = (uint)((wm + l31) & 15);
  const int wr = wn + l31;              // W n-row 0..63
  const uint bq = (uint)(wr >> 1);
  const uint bbase = bq * 256u;
  const uint bsel = (uint)((wr & 1) * 8);
  const uint bx = bq & 15u;

  v16f acc = {};

  auto stage = [&](int s, uint xb, uint wo) {
#pragma unroll
    for (int j = 0; j < 4; ++j)
      __builtin_amdgcn_global_load_lds(
          (const AS1 void*)(xsrc[j] + (size_t)s * BK),
          (AS3 void*)(smem + xb + xdst[j]), 16, 0, 0);
    __builtin_amdgcn_global_load_lds(
        (const AS1 void*)(wsrc + (size_t)s * BK),
        (AS3 void*)(smem + wo + wdst), 16, 0, 0);
  };

  // ---- prologue: x(0)+W(0) -> buffer 0
  stage(0, 0u, 65536u);
  __syncthreads();     // drains prologue DMA (one-time cost)

  // ---- main loop: ONE barrier per step, pure DMA + MFMA
  for (int t = 0; t < NSTEPS; ++t) {
    const uint xb = (uint)(t & 1) * 32768u;
    const uint wo = 65536u + (uint)(t & 1) * 8192u;
    if (t + 1 < NSTEPS) stage(t + 1, xb ^ 32768u, wo ^ 8192u);
    __builtin_amdgcn_sched_barrier(0);  // pin DMA issue above compute

#pragma unroll
    for (int kc = 0; kc < 4; ++kc) {
      const uint ch = (uint)(kc * 2 + hi5);
      v8s ah = *(const v8s*)(smem + xb + arow + ((ch ^ ax) << 4));
      v8s al = *(const v8s*)(smem + xb + arow + (((ch + 8u) ^ ax) << 4));
      v8s b  = *(const v8s*)(smem + wo + bbase + (((bsel + ch) ^ bx) << 4));
      acc = __builtin_amdgcn_mfma_f32_32x32x16_bf16(ah, b, acc, 0, 0, 0);
      acc = __builtin_amdgcn_mfma_f32_32x32x16_bf16(al, b, acc, 0, 0, 0);
    }

    __syncthreads();   // publish buf^1 (DMA had the whole compute to land)
  }

  // ---- epilogue: C/D col = lane&31, row = (reg&3) + 8*(reg>>2) + 4*(lane>>5)
  const int n = n0 + wn + l31;
  const float scl = scales[n];
#pragma unroll
  for (int reg = 0; reg < 16; ++reg) {
    const int m = m0 + wm + (reg & 3) + 8 * (reg >> 2) + 4 * hi5;
    out[(size_t)m * N_OUT + n] = acc[reg] * scl;
  }
}

// ---------------- fallback (workspace too small); also dtype-probed ----------------
__global__ void naive_kernel(const float* __restrict__ x, const void* __restrict__ wraw,
                             const float* __restrict__ scales, float* __restrict__ out) {
  const int* wi = (const int*)wraw;
  bool is32 = true;
  for (int i = 0; i < 16; ++i) { int v = wi[i]; is32 = is32 && v >= -128 && v <= 127; }
  const int idx = blockIdx.x * 256 + threadIdx.x;
  const int m = idx >> 14;
  const int n = idx & (N_OUT - 1);
  const float* xr = x + (size_t)m * K_IN;
  float acc = 0.f;
  if (is32) {
    const int* wr = wi + (size_t)n * K_IN;
    for (int k = 0; k < K_IN; ++k) acc += xr[k] * (float)wr[k];
  } else {
    const signed char* wr = (const signed char*)wraw + (size_t)n * K_IN;
    for (int k = 0; k < K_IN; ++k) acc += xr[k] * (float)wr[k];
  }
  out[idx] = acc * scales[n];
}

extern "C" void kernel_launch(void* const* d_in, const int* in_sizes, int n_in,
                              void* d_out, int out_size, void* d_ws, size_t ws_size,
                              hipStream_t stream) {
  const float* x = (const float*)d_in[0];
  const void* w = d_in[1];  // dtype resolved on-device (int8 vs int32 materialization)
  const float* scales = (const float*)d_in[2];
  float* out = (float*)d_out;
  const size_t XB = (size_t)M_TOK * K_IN;          // elements per x plane
  const size_t need = (2 * XB + (size_t)N_OUT * K_IN) * sizeof(unsigned short);
  if (ws_size >= need + (8u << 20)) {  // 132 MiB + slack (harness ws ~1 GiB per fills)
    unsigned short* xhi = (unsigned short*)d_ws;
    unsigned short* xlo = xhi + XB;
    unsigned short* wbf = xlo + XB;
    cast_kernel<<<(M_TOK * K_IN) / 1024, 256, 0, stream>>>(x, xhi, xlo);
    wcompact_kernel<<<((size_t)N_OUT * K_IN) / (16 * 256), 256, 0, stream>>>(w, wbf);
    gemm_kernel<<<512, 512, 0, stream>>>(xhi, xlo, wbf, scales, out);
  } else {
    naive_kernel<<<(M_TOK * N_OUT) / 256, 256, 0, stream>>>(x, w, scales, out);
  }
}